// Round 1
// baseline (162.539 us; speedup 1.0000x reference)
//
#include <hip/hip_runtime.h>
#include <hip/hip_bf16.h>

#define NDIM 16
#define HDIM 128
#define BATCH 256
#define EPS_D 1e-6f

// ---------------- Kernel 1: metric = sym(MLP(points)) + eps*I ----------------
__global__ __launch_bounds__(256) void metric_kernel(
    const float* __restrict__ points,
    const float* __restrict__ mW1, const float* __restrict__ mb1,
    const float* __restrict__ mW2, const float* __restrict__ mb2,
    float* __restrict__ metric) {
  int b = blockIdx.x;
  int t = threadIdx.x;
  __shared__ float p[16];
  __shared__ float mh[128];
  __shared__ float raw[256];
  if (t < 16) p[t] = points[b * 16 + t];
  __syncthreads();
  if (t < 128) {
    float acc = mb1[t];
#pragma unroll
    for (int k = 0; k < 16; ++k) acc = fmaf(p[k], mW1[k * 128 + t], acc);
    mh[t] = fmaxf(acc, 0.f);
  }
  __syncthreads();
  {
    float acc = mb2[t];
#pragma unroll 8
    for (int h = 0; h < 128; ++h) acc = fmaf(mh[h], mW2[h * 256 + t], acc);
    raw[t] = acc;
  }
  __syncthreads();
  int i = t >> 4, j = t & 15;
  float v = 0.5f * (raw[i * 16 + j] + raw[j * 16 + i]);
  if (i == j) v += EPS_D;
  metric[b * 256 + t] = v;
}

// ------- Kernel 2: per-b / per-(b,i) projections through rW1 blocks ---------
// A1[b,h]  = rb1[h] + sum_r points[b,r] * rW1[r,h]                (rows 0:16)
// Mi[b,i,h]=            sum_c metric[b,i,c] * rW1[16+c,h]         (rows 16:32)
// Mj[b,i,h]=            sum_c metric[b,i,c] * rW1[32+c,h]         (rows 32:48)
__global__ __launch_bounds__(256) void proj_kernel(
    const float* __restrict__ points,
    const float* __restrict__ metric,
    const float* __restrict__ rW1, const float* __restrict__ rb1,
    float* __restrict__ A1, float* __restrict__ Mi, float* __restrict__ Mj) {
  int b = blockIdx.x;
  int h = threadIdx.x;  // 0..255
  __shared__ float p[16];
  __shared__ float M[256];
  if (h < 16) p[h] = points[b * 16 + h];
  M[h] = metric[b * 256 + h];
  __syncthreads();
  float a = rb1[h];
#pragma unroll
  for (int r = 0; r < 16; ++r) a = fmaf(p[r], rW1[r * 256 + h], a);
  A1[b * 256 + h] = a;
  for (int i = 0; i < 16; ++i) {
    float mi = 0.f, mj = 0.f;
#pragma unroll
    for (int c = 0; c < 16; ++c) {
      float m = M[i * 16 + c];
      mi = fmaf(m, rW1[(16 + c) * 256 + h], mi);
      mj = fmaf(m, rW1[(32 + c) * 256 + h], mj);
    }
    Mi[(b * 16 + i) * 256 + h] = mi;
    Mj[(b * 16 + i) * 256 + h] = mj;
  }
}

// ---- Kernel 3: fused christoffel MLP + ricci layer-1 relu accumulation -----
// One block per (b,i). Computes christoffel[b,i,j,k] for all 256 (j,k) in LDS,
// then H2i[b,i,h] = sum_j relu(A1[b,h] + Mi[b,i,h] + Mj[b,j,h]
//                              + sum_k ch[j,k]*rW1[48+k,h])
__global__ __launch_bounds__(256) void chr_kernel(
    const float* __restrict__ metric,
    const float* __restrict__ cW1, const float* __restrict__ cb1,
    const float* __restrict__ cW2, const float* __restrict__ cb2,
    const float* __restrict__ rW1,
    const float* __restrict__ A1, const float* __restrict__ Mi,
    const float* __restrict__ Mj,
    float* __restrict__ H2i) {
  int bi = blockIdx.x;  // b*16 + i
  int b = bi >> 4, i = bi & 15;
  int t = threadIdx.x;  // 0..255
  __shared__ float M[256];
  __shared__ float ch[256];
  __shared__ float w1[384];
  __shared__ float b1[128];
  __shared__ float w2[128];
  __shared__ float rc[16 * 256];  // rW1 rows 48:64, [k][h]
  M[t] = metric[b * 256 + t];
  if (t < 128) {
    b1[t] = cb1[t];
    w2[t] = cW2[t];
  }
  if (t < 192) {
    w1[t] = cW1[t];
    w1[t + 192] = cW1[t + 192];
  }
#pragma unroll
  for (int k = 0; k < 16; ++k) rc[k * 256 + t] = rW1[(48 + k) * 256 + t];
  __syncthreads();

  // christoffel for triple (i, j=t>>4, k=t&15)
  {
    int j = t >> 4, k = t & 15;
    float x0 = M[i * 16 + j];
    float x1 = M[j * 16 + k];
    float x2 = M[k * 16 + i];
    float acc = cb2[0];
#pragma unroll 4
    for (int h = 0; h < 128; ++h) {
      float pre = fmaf(x0, w1[h], fmaf(x1, w1[128 + h], fmaf(x2, w1[256 + h], b1[h])));
      acc = fmaf(tanhf(pre), w2[h], acc);
    }
    ch[t] = acc;
  }
  __syncthreads();

  // layer-1 accumulate over j for hidden unit h = t
  {
    int h = t;
    float base = A1[b * 256 + h] + Mi[bi * 256 + h];
    float hacc = 0.f;
    for (int jj = 0; jj < 16; ++jj) {
      float cp = 0.f;
#pragma unroll
      for (int kk = 0; kk < 16; ++kk)
        cp = fmaf(ch[jj * 16 + kk], rc[kk * 256 + h], cp);
      float v = base + Mj[(b * 16 + jj) * 256 + h] + cp;
      hacc += fmaxf(v, 0.f);
    }
    H2i[bi * 256 + h] = hacc;
  }
}

// ------ Kernel 4: reduce over i, linear layer 2, symmetrize, scale ----------
__global__ __launch_bounds__(256) void final_kernel(
    const float* __restrict__ H2i,
    const float* __restrict__ rW2, const float* __restrict__ rb2,
    float* __restrict__ out) {
  int b = blockIdx.x;
  int t = threadIdx.x;
  __shared__ float G[256];
  __shared__ float T[256];
  float g = 0.f;
#pragma unroll
  for (int i = 0; i < 16; ++i) g += H2i[(b * 16 + i) * 256 + t];
  G[t] = g;
  __syncthreads();
  float acc = 256.f * rb2[t];
#pragma unroll 8
  for (int h = 0; h < 256; ++h) acc = fmaf(G[h], rW2[h * 256 + t], acc);
  T[t] = acc * (1.f / 256.f);
  __syncthreads();
  int k = t >> 4, l = t & 15;
  out[b * 256 + t] = 0.5f * (T[k * 16 + l] + T[l * 16 + k]);
}

extern "C" void kernel_launch(void* const* d_in, const int* in_sizes, int n_in,
                              void* d_out, int out_size, void* d_ws, size_t ws_size,
                              hipStream_t stream) {
  const float* points = (const float*)d_in[0];
  const float* mW1 = (const float*)d_in[1];
  const float* mb1 = (const float*)d_in[2];
  const float* mW2 = (const float*)d_in[3];
  const float* mb2 = (const float*)d_in[4];
  const float* cW1 = (const float*)d_in[5];
  const float* cb1 = (const float*)d_in[6];
  const float* cW2 = (const float*)d_in[7];
  const float* cb2 = (const float*)d_in[8];
  const float* rW1 = (const float*)d_in[9];
  const float* rb1 = (const float*)d_in[10];
  const float* rW2 = (const float*)d_in[11];
  const float* rb2 = (const float*)d_in[12];
  float* out = (float*)d_out;

  float* ws = (float*)d_ws;
  float* metric = ws;                 // 256*256           = 65536
  float* A1 = metric + 65536;         // 256*256           = 65536
  float* Mi = A1 + 65536;             // 256*16*256        = 1048576
  float* Mj = Mi + 1048576;           // 1048576
  float* H2i = Mj + 1048576;          // 1048576
  // total: 3,276,800 floats = 12.5 MB of d_ws

  metric_kernel<<<BATCH, 256, 0, stream>>>(points, mW1, mb1, mW2, mb2, metric);
  proj_kernel<<<BATCH, 256, 0, stream>>>(points, metric, rW1, rb1, A1, Mi, Mj);
  chr_kernel<<<BATCH * NDIM, 256, 0, stream>>>(metric, cW1, cb1, cW2, cb2, rW1,
                                               A1, Mi, Mj, H2i);
  final_kernel<<<BATCH, 256, 0, stream>>>(H2i, rW2, rb2, out);
}

// Round 2
// 145.668 us; speedup vs baseline: 1.1158x; 1.1158x over previous
//
#include <hip/hip_runtime.h>
#include <hip/hip_bf16.h>

#define NDIM 16
#define HDIM 128
#define BATCH 256
#define EPS_D 1e-6f

// ---- Kernel 1: metric = sym(MLP(points)) + eps*I, then rW1 block projections
// A1[b,h]  = rb1[h] + sum_r points[b,r] * rW1[r,h]                (rows 0:16)
// Mi[b,i,h]=            sum_c metric[b,i,c] * rW1[16+c,h]         (rows 16:32)
// Mj[b,i,h]=            sum_c metric[b,i,c] * rW1[32+c,h]         (rows 32:48)
__global__ __launch_bounds__(256) void metric_proj_kernel(
    const float* __restrict__ points,
    const float* __restrict__ mW1, const float* __restrict__ mb1,
    const float* __restrict__ mW2, const float* __restrict__ mb2,
    const float* __restrict__ rW1, const float* __restrict__ rb1,
    float* __restrict__ metric,
    float* __restrict__ A1, float* __restrict__ Mi, float* __restrict__ Mj) {
  int b = blockIdx.x;
  int t = threadIdx.x;  // 0..255
  __shared__ float p[16];
  __shared__ float mh[128];
  __shared__ float raw[256];
  __shared__ float M[256];
  if (t < 16) p[t] = points[b * 16 + t];
  __syncthreads();
  if (t < 128) {
    float acc = mb1[t];
#pragma unroll
    for (int k = 0; k < 16; ++k) acc = fmaf(p[k], mW1[k * 128 + t], acc);
    mh[t] = fmaxf(acc, 0.f);
  }
  __syncthreads();
  {
    float acc = mb2[t];
#pragma unroll 8
    for (int h = 0; h < 128; ++h) acc = fmaf(mh[h], mW2[h * 256 + t], acc);
    raw[t] = acc;
  }
  __syncthreads();
  {
    int i = t >> 4, j = t & 15;
    float v = 0.5f * (raw[i * 16 + j] + raw[j * 16 + i]);
    if (i == j) v += EPS_D;
    M[t] = v;
    metric[b * 256 + t] = v;
  }
  __syncthreads();
  // ---- projections: h = t ----
  {
    int h = t;
    float wB[16], wC[16];
#pragma unroll
    for (int c = 0; c < 16; ++c) {
      wB[c] = rW1[(16 + c) * 256 + h];
      wC[c] = rW1[(32 + c) * 256 + h];
    }
    float a = rb1[h];
#pragma unroll
    for (int r = 0; r < 16; ++r) a = fmaf(p[r], rW1[r * 256 + h], a);
    A1[b * 256 + h] = a;
#pragma unroll 2
    for (int i = 0; i < 16; ++i) {
      float mi = 0.f, mj = 0.f;
#pragma unroll
      for (int c = 0; c < 16; ++c) {
        float m = M[i * 16 + c];
        mi = fmaf(m, wB[c], mi);
        mj = fmaf(m, wC[c], mj);
      }
      Mi[(b * 16 + i) * 256 + h] = mi;
      Mj[(b * 16 + i) * 256 + h] = mj;
    }
  }
}

// ---- Kernel 2: fused christoffel MLP + ricci layer-1 relu accumulation -----
// One block of 128 threads per (b,i); each thread handles 2 (j,k) triples and
// 2 hidden units. tanh(x) = 1 - 2/(exp(2x)+1), with 2*log2(e) folded into the
// LDS copy of cW1/cb1 so exp(2x) is a single v_exp_f32.
__global__ __launch_bounds__(128) void chr_kernel(
    const float* __restrict__ metric,
    const float* __restrict__ cW1, const float* __restrict__ cb1,
    const float* __restrict__ cW2, const float* __restrict__ cb2,
    const float* __restrict__ rW1,
    const float* __restrict__ A1, const float* __restrict__ Mi,
    const float* __restrict__ Mj,
    float* __restrict__ H2i) {
  int bi = blockIdx.x;  // b*16 + i
  int b = bi >> 4, i = bi & 15;
  int t = threadIdx.x;  // 0..127
  __shared__ float M[256];
  __shared__ float4 q[128];   // {s*w1_0h, s*w1_1h, s*w1_2h, s*b1h}, s = 2*log2e
  __shared__ float w2[128];
  __shared__ float ch[256];
  M[t] = metric[b * 256 + t];
  M[t + 128] = metric[b * 256 + t + 128];
  {
    const float S = 2.8853900817779268f;  // 2 * log2(e)
    q[t] = make_float4(S * cW1[t], S * cW1[128 + t], S * cW1[256 + t],
                       S * cb1[t]);
    w2[t] = cW2[t];
  }
  __syncthreads();

  // ---- phase 1: christoffel for triples t and t+128 ----
  {
    int j0 = t >> 4, k0 = t & 15;
    int j1 = j0 + 8, k1 = k0;
    float x00 = M[i * 16 + j0], x01 = M[j0 * 16 + k0], x02 = M[k0 * 16 + i];
    float x10 = M[i * 16 + j1], x11 = M[j1 * 16 + k1], x12 = M[k1 * 16 + i];
    float c2 = cb2[0];
    float acc0 = c2, acc1 = c2;
#pragma unroll 4
    for (int h = 0; h < 128; ++h) {
      float4 Q = q[h];
      float w = w2[h];
      float pre0 = fmaf(x00, Q.x, fmaf(x01, Q.y, fmaf(x02, Q.z, Q.w)));
      float pre1 = fmaf(x10, Q.x, fmaf(x11, Q.y, fmaf(x12, Q.z, Q.w)));
      float e0 = __builtin_amdgcn_exp2f(pre0);
      float e1 = __builtin_amdgcn_exp2f(pre1);
      float r0 = __builtin_amdgcn_rcpf(e0 + 1.f);
      float r1 = __builtin_amdgcn_rcpf(e1 + 1.f);
      float th0 = fmaf(-2.f, r0, 1.f);
      float th1 = fmaf(-2.f, r1, 1.f);
      acc0 = fmaf(th0, w, acc0);
      acc1 = fmaf(th1, w, acc1);
    }
    ch[t] = acc0;
    ch[t + 128] = acc1;
  }
  __syncthreads();

  // ---- phase 2: H2i[bi,h] for h = t and t+128 ----
  {
    int h0 = t, h1 = t + 128;
    float rc0[16], rc1[16];
#pragma unroll
    for (int kk = 0; kk < 16; ++kk) {
      rc0[kk] = rW1[(48 + kk) * 256 + h0];
      rc1[kk] = rW1[(48 + kk) * 256 + h1];
    }
    float base0 = A1[b * 256 + h0] + Mi[bi * 256 + h0];
    float base1 = A1[b * 256 + h1] + Mi[bi * 256 + h1];
    float hacc0 = 0.f, hacc1 = 0.f;
#pragma unroll 2
    for (int jj = 0; jj < 16; ++jj) {
      float cp0 = 0.f, cp1 = 0.f;
#pragma unroll
      for (int kk = 0; kk < 16; ++kk) {
        float c = ch[jj * 16 + kk];
        cp0 = fmaf(c, rc0[kk], cp0);
        cp1 = fmaf(c, rc1[kk], cp1);
      }
      float mj0 = Mj[(b * 16 + jj) * 256 + h0];
      float mj1 = Mj[(b * 16 + jj) * 256 + h1];
      hacc0 += fmaxf(base0 + mj0 + cp0, 0.f);
      hacc1 += fmaxf(base1 + mj1 + cp1, 0.f);
    }
    H2i[bi * 256 + h0] = hacc0;
    H2i[bi * 256 + h1] = hacc1;
  }
}

// ---- Kernel 3: reduce over i, linear layer 2, symmetrize, scale ------------
__global__ __launch_bounds__(256) void final_kernel(
    const float* __restrict__ H2i,
    const float* __restrict__ rW2, const float* __restrict__ rb2,
    float* __restrict__ out) {
  int b = blockIdx.x;
  int t = threadIdx.x;
  __shared__ float G[256];
  __shared__ float T[256];
  float g = 0.f;
#pragma unroll
  for (int i = 0; i < 16; ++i) g += H2i[(b * 16 + i) * 256 + t];
  G[t] = g;
  __syncthreads();
  float acc = 256.f * rb2[t];
#pragma unroll 8
  for (int h = 0; h < 256; ++h) acc = fmaf(G[h], rW2[h * 256 + t], acc);
  T[t] = acc * (1.f / 256.f);
  __syncthreads();
  int k = t >> 4, l = t & 15;
  out[b * 256 + t] = 0.5f * (T[k * 16 + l] + T[l * 16 + k]);
}

extern "C" void kernel_launch(void* const* d_in, const int* in_sizes, int n_in,
                              void* d_out, int out_size, void* d_ws, size_t ws_size,
                              hipStream_t stream) {
  const float* points = (const float*)d_in[0];
  const float* mW1 = (const float*)d_in[1];
  const float* mb1 = (const float*)d_in[2];
  const float* mW2 = (const float*)d_in[3];
  const float* mb2 = (const float*)d_in[4];
  const float* cW1 = (const float*)d_in[5];
  const float* cb1 = (const float*)d_in[6];
  const float* cW2 = (const float*)d_in[7];
  const float* cb2 = (const float*)d_in[8];
  const float* rW1 = (const float*)d_in[9];
  const float* rb1 = (const float*)d_in[10];
  const float* rW2 = (const float*)d_in[11];
  const float* rb2 = (const float*)d_in[12];
  float* out = (float*)d_out;

  float* ws = (float*)d_ws;
  float* metric = ws;                 // 65536
  float* A1 = metric + 65536;         // 65536
  float* Mi = A1 + 65536;             // 1048576
  float* Mj = Mi + 1048576;           // 1048576
  float* H2i = Mj + 1048576;          // 1048576

  metric_proj_kernel<<<BATCH, 256, 0, stream>>>(points, mW1, mb1, mW2, mb2,
                                                rW1, rb1, metric, A1, Mi, Mj);
  chr_kernel<<<BATCH * NDIM, 128, 0, stream>>>(metric, cW1, cb1, cW2, cb2, rW1,
                                               A1, Mi, Mj, H2i);
  final_kernel<<<BATCH, 256, 0, stream>>>(H2i, rW2, rb2, out);
}

// Round 3
// 143.648 us; speedup vs baseline: 1.1315x; 1.0141x over previous
//
#include <hip/hip_runtime.h>
#include <hip/hip_bf16.h>

#define NDIM 16
#define HDIM 128
#define BATCH 256
#define EPS_D 1e-6f

// ---- Kernel 1: metric = sym(MLP(points)) + eps*I, rW1 block projections,
//      and zero-init of the G accumulator (ws is poisoned 0xAA each launch).
__global__ __launch_bounds__(256) void metric_proj_kernel(
    const float* __restrict__ points,
    const float* __restrict__ mW1, const float* __restrict__ mb1,
    const float* __restrict__ mW2, const float* __restrict__ mb2,
    const float* __restrict__ rW1, const float* __restrict__ rb1,
    float* __restrict__ metric,
    float* __restrict__ A1, float* __restrict__ Mi, float* __restrict__ Mj,
    float* __restrict__ G) {
  int b = blockIdx.x;
  int t = threadIdx.x;  // 0..255
  __shared__ float p[16];
  __shared__ float mh[128];
  __shared__ float raw[256];
  __shared__ float M[256];
  G[b * 256 + t] = 0.f;
  if (t < 16) p[t] = points[b * 16 + t];
  __syncthreads();
  if (t < 128) {
    float acc = mb1[t];
#pragma unroll
    for (int k = 0; k < 16; ++k) acc = fmaf(p[k], mW1[k * 128 + t], acc);
    mh[t] = fmaxf(acc, 0.f);
  }
  __syncthreads();
  {
    float acc = mb2[t];
#pragma unroll 8
    for (int h = 0; h < 128; ++h) acc = fmaf(mh[h], mW2[h * 256 + t], acc);
    raw[t] = acc;
  }
  __syncthreads();
  {
    int i = t >> 4, j = t & 15;
    float v = 0.5f * (raw[i * 16 + j] + raw[j * 16 + i]);
    if (i == j) v += EPS_D;
    M[t] = v;
    metric[b * 256 + t] = v;
  }
  __syncthreads();
  {
    int h = t;
    float wB[16], wC[16];
#pragma unroll
    for (int c = 0; c < 16; ++c) {
      wB[c] = rW1[(16 + c) * 256 + h];
      wC[c] = rW1[(32 + c) * 256 + h];
    }
    float a = rb1[h];
#pragma unroll
    for (int r = 0; r < 16; ++r) a = fmaf(p[r], rW1[r * 256 + h], a);
    A1[b * 256 + h] = a;
#pragma unroll 2
    for (int i = 0; i < 16; ++i) {
      float mi = 0.f, mj = 0.f;
#pragma unroll
      for (int c = 0; c < 16; ++c) {
        float m = M[i * 16 + c];
        mi = fmaf(m, wB[c], mi);
        mj = fmaf(m, wC[c], mj);
      }
      Mi[(b * 16 + i) * 256 + h] = mi;
      Mj[(b * 16 + i) * 256 + h] = mj;
    }
  }
}

// ---- Kernel 2: fused christoffel MLP + ricci layer-1 relu + i-reduction ----
// Block = 4 waves, one wave per i (i = g*4 + wave), 4 blocks per b.
// Each lane: 4 triples (phase 1), then 4 hidden units (phase 2).
// No inter-phase barrier: each wave's ch tile is private.
// tanh(x) = 1 - 2/(exp2(S*x')+1) with S=2*log2(e) folded into LDS weights.
__global__ __launch_bounds__(256, 4) void chr_kernel(
    const float* __restrict__ metric,
    const float* __restrict__ cW1, const float* __restrict__ cb1,
    const float* __restrict__ cW2, const float* __restrict__ cb2,
    const float* __restrict__ rW1,
    const float* __restrict__ A1, const float* __restrict__ Mi,
    const float* __restrict__ Mj,
    float* __restrict__ G) {
  int blk = blockIdx.x;        // b*4 + g
  int b = blk >> 2, g = blk & 3;
  int t = threadIdx.x;         // 0..255
  int w = t >> 6, l = t & 63;  // wave, lane
  int i = g * 4 + w;
  int bi = b * 16 + i;
  __shared__ float M[256];
  __shared__ float4 z[128];    // {S*w1_0h, S*w1_1h, S*w1_2h, S*b1h}
  __shared__ float4 w2p[32];   // cW2 packed 4-wide
  __shared__ float4 ch4[256];  // per-wave ch tiles: wave w owns [w*64, w*64+64)
  float* chf = (float*)ch4;
  M[t] = metric[b * 256 + t];
  if (t < 128) {
    const float S = 2.8853900817779268f;  // 2 * log2(e)
    z[t] = make_float4(S * cW1[t], S * cW1[128 + t], S * cW1[256 + t],
                       S * cb1[t]);
  } else {
    ((float*)w2p)[t - 128] = cW2[t - 128];
  }
  __syncthreads();

  // ---- phase 1: 4 triples per lane: jk = l + 64*m ----
  {
    float x0[4], x1[4], x2[4], acc[4];
    float c2 = cb2[0];
#pragma unroll
    for (int m = 0; m < 4; ++m) {
      int jk = l + 64 * m;
      int j = jk >> 4, k = jk & 15;
      x0[m] = M[i * 16 + j];
      x1[m] = M[j * 16 + k];
      x2[m] = M[k * 16 + i];
      acc[m] = c2;
    }
    for (int h = 0; h < 128; h += 4) {
      float4 W2 = w2p[h >> 2];
      float w2u[4] = {W2.x, W2.y, W2.z, W2.w};
#pragma unroll
      for (int u = 0; u < 4; ++u) {
        float4 Q = z[h + u];
#pragma unroll
        for (int m = 0; m < 4; ++m) {
          float pre = fmaf(x0[m], Q.x, fmaf(x1[m], Q.y, fmaf(x2[m], Q.z, Q.w)));
          float e = __builtin_amdgcn_exp2f(pre);
          float r = __builtin_amdgcn_rcpf(e + 1.f);
          acc[m] = fmaf(w2u[u], fmaf(-2.f, r, 1.f), acc[m]);
        }
      }
    }
#pragma unroll
    for (int m = 0; m < 4; ++m) chf[w * 256 + l + 64 * m] = acc[m];
  }
  // no __syncthreads(): each wave reads only its own ch tile (compiler orders
  // the wave's own ds_write -> ds_read via lgkmcnt).

  // ---- phase 2: 4 hidden units per lane: h_m = l + 64*m ----
  {
    float rc[4][16];
#pragma unroll
    for (int kk = 0; kk < 16; ++kk) {
#pragma unroll
      for (int m = 0; m < 4; ++m)
        rc[m][kk] = rW1[(48 + kk) * 256 + l + 64 * m];
    }
    float base[4], hacc[4];
#pragma unroll
    for (int m = 0; m < 4; ++m) {
      int h = l + 64 * m;
      base[m] = A1[b * 256 + h] + Mi[bi * 256 + h];
      hacc[m] = 0.f;
    }
    for (int jj = 0; jj < 16; ++jj) {
      float4 c0 = ch4[w * 64 + jj * 4 + 0];
      float4 c1 = ch4[w * 64 + jj * 4 + 1];
      float4 c2v = ch4[w * 64 + jj * 4 + 2];
      float4 c3 = ch4[w * 64 + jj * 4 + 3];
      float cc[16] = {c0.x, c0.y, c0.z, c0.w, c1.x, c1.y, c1.z, c1.w,
                      c2v.x, c2v.y, c2v.z, c2v.w, c3.x, c3.y, c3.z, c3.w};
#pragma unroll
      for (int m = 0; m < 4; ++m) {
        float cp = 0.f;
#pragma unroll
        for (int kk = 0; kk < 16; ++kk) cp = fmaf(cc[kk], rc[m][kk], cp);
        float mj = Mj[(b * 16 + jj) * 256 + l + 64 * m];
        hacc[m] += fmaxf(base[m] + mj + cp, 0.f);
      }
    }
#pragma unroll
    for (int m = 0; m < 4; ++m)
      atomicAdd(&G[b * 256 + l + 64 * m], hacc[m]);
  }
}

// ---- Kernel 3: linear layer 2 on G, symmetrize, scale ----------------------
__global__ __launch_bounds__(256) void final_kernel(
    const float* __restrict__ G,
    const float* __restrict__ rW2, const float* __restrict__ rb2,
    float* __restrict__ out) {
  int b = blockIdx.x;
  int t = threadIdx.x;
  __shared__ float4 Gs[64];
  __shared__ float T[256];
  if (t < 64) Gs[t] = ((const float4*)(G + b * 256))[t];
  __syncthreads();
  float acc = 256.f * rb2[t];
#pragma unroll 4
  for (int h4 = 0; h4 < 64; ++h4) {
    float4 gg = Gs[h4];
    acc = fmaf(gg.x, rW2[(h4 * 4 + 0) * 256 + t], acc);
    acc = fmaf(gg.y, rW2[(h4 * 4 + 1) * 256 + t], acc);
    acc = fmaf(gg.z, rW2[(h4 * 4 + 2) * 256 + t], acc);
    acc = fmaf(gg.w, rW2[(h4 * 4 + 3) * 256 + t], acc);
  }
  T[t] = acc * (1.f / 256.f);
  __syncthreads();
  int k = t >> 4, lcol = t & 15;
  out[b * 256 + t] = 0.5f * (T[k * 16 + lcol] + T[lcol * 16 + k]);
}

extern "C" void kernel_launch(void* const* d_in, const int* in_sizes, int n_in,
                              void* d_out, int out_size, void* d_ws, size_t ws_size,
                              hipStream_t stream) {
  const float* points = (const float*)d_in[0];
  const float* mW1 = (const float*)d_in[1];
  const float* mb1 = (const float*)d_in[2];
  const float* mW2 = (const float*)d_in[3];
  const float* mb2 = (const float*)d_in[4];
  const float* cW1 = (const float*)d_in[5];
  const float* cb1 = (const float*)d_in[6];
  const float* cW2 = (const float*)d_in[7];
  const float* cb2 = (const float*)d_in[8];
  const float* rW1 = (const float*)d_in[9];
  const float* rb1 = (const float*)d_in[10];
  const float* rW2 = (const float*)d_in[11];
  const float* rb2 = (const float*)d_in[12];
  float* out = (float*)d_out;

  float* ws = (float*)d_ws;
  float* metric = ws;                 // 65536
  float* A1 = metric + 65536;         // 65536
  float* Mi = A1 + 65536;             // 1048576
  float* Mj = Mi + 1048576;           // 1048576
  float* G = Mj + 1048576;            // 65536

  metric_proj_kernel<<<BATCH, 256, 0, stream>>>(points, mW1, mb1, mW2, mb2,
                                                rW1, rb1, metric, A1, Mi, Mj, G);
  chr_kernel<<<BATCH * 4, 256, 0, stream>>>(metric, cW1, cb1, cW2, cb2, rW1,
                                            A1, Mi, Mj, G);
  final_kernel<<<BATCH, 256, 0, stream>>>(G, rW2, rb2, out);
}

// Round 4
// 135.717 us; speedup vs baseline: 1.1976x; 1.0584x over previous
//
#include <hip/hip_runtime.h>
#include <hip/hip_bf16.h>

#define NDIM 16
#define HDIM 128
#define BATCH 256
#define EPS_D 1e-6f

typedef float v2f __attribute__((ext_vector_type(2)));
static __device__ __forceinline__ v2f v2(float a, float b) {
  v2f r; r.x = a; r.y = b; return r;
}
static __device__ __forceinline__ v2f splat(float a) {
  v2f r; r.x = a; r.y = a; return r;
}

// ---- Kernel 1: metric = sym(MLP(points)) + eps*I, rW1 block projections,
//      and zero-init of the G accumulator.
__global__ __launch_bounds__(256) void metric_proj_kernel(
    const float* __restrict__ points,
    const float* __restrict__ mW1, const float* __restrict__ mb1,
    const float* __restrict__ mW2, const float* __restrict__ mb2,
    const float* __restrict__ rW1, const float* __restrict__ rb1,
    float* __restrict__ metric,
    float* __restrict__ A1, float* __restrict__ Mi, float* __restrict__ Mj,
    float* __restrict__ G) {
  int b = blockIdx.x;
  int t = threadIdx.x;  // 0..255
  __shared__ float p[16];
  __shared__ float mh[128];
  __shared__ float raw[256];
  __shared__ float M[256];
  G[b * 256 + t] = 0.f;
  if (t < 16) p[t] = points[b * 16 + t];
  __syncthreads();
  if (t < 128) {
    float acc = mb1[t];
#pragma unroll
    for (int k = 0; k < 16; ++k) acc = fmaf(p[k], mW1[k * 128 + t], acc);
    mh[t] = fmaxf(acc, 0.f);
  }
  __syncthreads();
  {
    float acc = mb2[t];
#pragma unroll 8
    for (int h = 0; h < 128; ++h) acc = fmaf(mh[h], mW2[h * 256 + t], acc);
    raw[t] = acc;
  }
  __syncthreads();
  {
    int i = t >> 4, j = t & 15;
    float v = 0.5f * (raw[i * 16 + j] + raw[j * 16 + i]);
    if (i == j) v += EPS_D;
    M[t] = v;
    metric[b * 256 + t] = v;
  }
  __syncthreads();
  {
    int h = t;
    float wB[16], wC[16];
#pragma unroll
    for (int c = 0; c < 16; ++c) {
      wB[c] = rW1[(16 + c) * 256 + h];
      wC[c] = rW1[(32 + c) * 256 + h];
    }
    float a = rb1[h];
#pragma unroll
    for (int r = 0; r < 16; ++r) a = fmaf(p[r], rW1[r * 256 + h], a);
    A1[b * 256 + h] = a;
#pragma unroll 2
    for (int i = 0; i < 16; ++i) {
      float mi = 0.f, mj = 0.f;
#pragma unroll
      for (int c = 0; c < 16; ++c) {
        float m = M[i * 16 + c];
        mi = fmaf(m, wB[c], mi);
        mj = fmaf(m, wC[c], mj);
      }
      Mi[(b * 16 + i) * 256 + h] = mi;
      Mj[(b * 16 + i) * 256 + h] = mj;
    }
  }
}

// ---- Kernel 2: fused christoffel MLP + ricci layer-1 relu + i-reduction ----
// One 128-thread block (2 waves) per (b,i). Wave w computes triples
// jk in [128w, 128w+128) as a float2 pair per lane (phase 1), then hidden
// units h0=128w+l, h1=h0+64 as a float2 pair (phase 2). All inner math uses
// packed fp32 (v_pk_fma_f32 etc.) via float2 ext-vectors.
// tanh(x) = 1 - 2/(exp2(S*x)+1), S = 2*log2(e) folded into LDS weights.
__global__ __launch_bounds__(128, 6) void chr_kernel(
    const float* __restrict__ metric,
    const float* __restrict__ cW1, const float* __restrict__ cb1,
    const float* __restrict__ cW2, const float* __restrict__ cb2,
    const float* __restrict__ rW1,
    const float* __restrict__ A1, const float* __restrict__ Mi,
    const float* __restrict__ Mj,
    float* __restrict__ G) {
  int bi = blockIdx.x;         // b*16 + i
  int b = bi >> 4, i = bi & 15;
  int t = threadIdx.x;         // 0..127
  int w = t >> 6, l = t & 63;  // wave, lane
  __shared__ float M[256];
  __shared__ float4 z[128];    // {S*w1_0h, S*w1_1h, S*w1_2h, S*b1h}
  __shared__ float4 w2p[32];   // cW2 packed 4-wide
  __shared__ float4 ch4[64];   // christoffel tile (256 floats)
  float* chf = (float*)ch4;
  M[t] = metric[b * 256 + t];
  M[t + 128] = metric[b * 256 + t + 128];
  {
    const float S = 2.8853900817779268f;  // 2 * log2(e)
    z[t] = make_float4(S * cW1[t], S * cW1[128 + t], S * cW1[256 + t],
                       S * cb1[t]);
    ((float*)w2p)[t] = cW2[t];
  }
  __syncthreads();

  // ---- phase 1: 2 triples per lane: jk0 = 128w + l, jk1 = jk0 + 64 ----
  {
    int jk0 = w * 128 + l, jk1 = jk0 + 64;
    int j0 = jk0 >> 4, k0 = jk0 & 15;
    int j1 = jk1 >> 4, k1 = jk1 & 15;
    v2f x0 = v2(M[i * 16 + j0], M[i * 16 + j1]);
    v2f x1 = v2(M[j0 * 16 + k0], M[j1 * 16 + k1]);
    v2f x2 = v2(M[k0 * 16 + i], M[k1 * 16 + i]);
    v2f acc = splat(cb2[0]);
    for (int hq = 0; hq < 32; ++hq) {
      float4 W2 = w2p[hq];
      float w2u[4] = {W2.x, W2.y, W2.z, W2.w};
#pragma unroll
      for (int u = 0; u < 4; ++u) {
        float4 Q = z[hq * 4 + u];
        v2f pre = __builtin_elementwise_fma(
            x0, splat(Q.x),
            __builtin_elementwise_fma(
                x1, splat(Q.y),
                __builtin_elementwise_fma(x2, splat(Q.z), splat(Q.w))));
        v2f e;
        e.x = __builtin_amdgcn_exp2f(pre.x);
        e.y = __builtin_amdgcn_exp2f(pre.y);
        v2f ep = e + splat(1.f);
        v2f r;
        r.x = __builtin_amdgcn_rcpf(ep.x);
        r.y = __builtin_amdgcn_rcpf(ep.y);
        v2f th = __builtin_elementwise_fma(splat(-2.f), r, splat(1.f));
        acc = __builtin_elementwise_fma(th, splat(w2u[u]), acc);
      }
    }
    chf[jk0] = acc.x;
    chf[jk1] = acc.y;
  }
  __syncthreads();

  // ---- phase 2: 2 hidden units per lane: h0 = 128w + l, h1 = h0 + 64 ----
  {
    int h0 = w * 128 + l, h1 = h0 + 64;
    v2f rc2[16];
#pragma unroll
    for (int kk = 0; kk < 16; ++kk)
      rc2[kk] = v2(rW1[(48 + kk) * 256 + h0], rW1[(48 + kk) * 256 + h1]);
    v2f base = v2(A1[b * 256 + h0] + Mi[bi * 256 + h0],
                  A1[b * 256 + h1] + Mi[bi * 256 + h1]);
    v2f hacc = splat(0.f);
    for (int jj = 0; jj < 16; ++jj) {
      float4 c0 = ch4[jj * 4 + 0];
      float4 c1 = ch4[jj * 4 + 1];
      float4 c2v = ch4[jj * 4 + 2];
      float4 c3 = ch4[jj * 4 + 3];
      v2f mj = v2(Mj[(b * 16 + jj) * 256 + h0], Mj[(b * 16 + jj) * 256 + h1]);
      v2f cp = base + mj;
      float cc[16] = {c0.x, c0.y, c0.z, c0.w, c1.x, c1.y, c1.z, c1.w,
                      c2v.x, c2v.y, c2v.z, c2v.w, c3.x, c3.y, c3.z, c3.w};
#pragma unroll
      for (int kk = 0; kk < 16; ++kk)
        cp = __builtin_elementwise_fma(splat(cc[kk]), rc2[kk], cp);
      v2f rl;
      rl.x = fmaxf(cp.x, 0.f);
      rl.y = fmaxf(cp.y, 0.f);
      hacc += rl;
    }
    atomicAdd(&G[b * 256 + h0], hacc.x);
    atomicAdd(&G[b * 256 + h1], hacc.y);
  }
}

// ---- Kernel 3: linear layer 2 on G, symmetrize, scale ----------------------
__global__ __launch_bounds__(256) void final_kernel(
    const float* __restrict__ G,
    const float* __restrict__ rW2, const float* __restrict__ rb2,
    float* __restrict__ out) {
  int b = blockIdx.x;
  int t = threadIdx.x;
  __shared__ float4 Gs[64];
  __shared__ float T[256];
  if (t < 64) Gs[t] = ((const float4*)(G + b * 256))[t];
  __syncthreads();
  float acc = 256.f * rb2[t];
#pragma unroll 4
  for (int h4 = 0; h4 < 64; ++h4) {
    float4 gg = Gs[h4];
    acc = fmaf(gg.x, rW2[(h4 * 4 + 0) * 256 + t], acc);
    acc = fmaf(gg.y, rW2[(h4 * 4 + 1) * 256 + t], acc);
    acc = fmaf(gg.z, rW2[(h4 * 4 + 2) * 256 + t], acc);
    acc = fmaf(gg.w, rW2[(h4 * 4 + 3) * 256 + t], acc);
  }
  T[t] = acc * (1.f / 256.f);
  __syncthreads();
  int k = t >> 4, lcol = t & 15;
  out[b * 256 + t] = 0.5f * (T[k * 16 + lcol] + T[lcol * 16 + k]);
}

extern "C" void kernel_launch(void* const* d_in, const int* in_sizes, int n_in,
                              void* d_out, int out_size, void* d_ws, size_t ws_size,
                              hipStream_t stream) {
  const float* points = (const float*)d_in[0];
  const float* mW1 = (const float*)d_in[1];
  const float* mb1 = (const float*)d_in[2];
  const float* mW2 = (const float*)d_in[3];
  const float* mb2 = (const float*)d_in[4];
  const float* cW1 = (const float*)d_in[5];
  const float* cb1 = (const float*)d_in[6];
  const float* cW2 = (const float*)d_in[7];
  const float* cb2 = (const float*)d_in[8];
  const float* rW1 = (const float*)d_in[9];
  const float* rb1 = (const float*)d_in[10];
  const float* rW2 = (const float*)d_in[11];
  const float* rb2 = (const float*)d_in[12];
  float* out = (float*)d_out;

  float* ws = (float*)d_ws;
  float* metric = ws;                 // 65536
  float* A1 = metric + 65536;         // 65536
  float* Mi = A1 + 65536;             // 1048576
  float* Mj = Mi + 1048576;           // 1048576
  float* G = Mj + 1048576;            // 65536

  metric_proj_kernel<<<BATCH, 256, 0, stream>>>(points, mW1, mb1, mW2, mb2,
                                                rW1, rb1, metric, A1, Mi, Mj, G);
  chr_kernel<<<BATCH * NDIM, 128, 0, stream>>>(metric, cW1, cb1, cW2, cb2, rW1,
                                               A1, Mi, Mj, G);
  final_kernel<<<BATCH, 256, 0, stream>>>(G, rW2, rb2, out);
}